// Round 1
// baseline (951.792 us; speedup 1.0000x reference)
//
#include <hip/hip_runtime.h>

// TrPredictor round 13 = r12 + register-resident MLP + register-resident Q.
// Operand-swap (the Phase-C S^T trick) applied to the two remaining LDS
// round trips:
//  - Phase E: H^T = MF(W1^T, N^T) computed in C-layout, silu in-register,
//    C-quad pairs concatenated into the B-operand of O^T = MF(W2^T, H^T).
//    w2 fragments precomputed with the matching permuted k-order.
//    No qm LDS scratch (was 16 ds_write_b16 + 2 ld8 per chunk per tile).
//  - Phase B: Q^T = MF(bwq, an) packed straight into the S^T B-operand;
//    K read as cat44(quad*4, 16+quad*4) halves so k-orders match.
// Phases A/C/D epilogues and head unchanged from r12 (924 us verified).

#define SS   201
#define SP   208
#define NMT  13
#define EE   32
#define HIDN 512
#define NTRL 4
#define CWN  16
#define BB   4096
#define XST  36
#define VWST 228

#define X_OFF    0
#define K_OFF    14976
#define VWT_OFF  29952   // VW^T [32][228]
#define QS_OFF   44544   // final-head reduction scratch only
#define MS_OFF   49152
#define RS_OFF   49984
#define BIAS_OFF 50816
#define SMEM_SZ  51840

#define WS_FRAG  0        // 288 tiles x 1024 B; per layer: 0,1=q 2,3=k 4,5=wvo 6,7=unused
#define WS_BIAS  294912
#define WS_B1    299008
#define WS_FIN   307200
#define L2E      1.4426950408889634f

typedef unsigned short u16;
typedef unsigned int   u32;
typedef short bf16x4 __attribute__((ext_vector_type(4)));
typedef short bf16x8 __attribute__((ext_vector_type(8)));
typedef float f32x4  __attribute__((ext_vector_type(4)));
typedef float f32x2  __attribute__((ext_vector_type(2)));

__device__ __forceinline__ f32x4 MF(bf16x8 a, bf16x8 b, f32x4 c){
  return __builtin_amdgcn_mfma_f32_16x16x32_bf16(a, b, c, 0, 0, 0);
}
__device__ __forceinline__ float bf2f(u16 u){ return __uint_as_float(((u32)u)<<16); }
__device__ __forceinline__ u16 f2bf(float f){            // exact RNE (cold paths)
  u32 u = __float_as_uint(f);
  u += 0x7fffu + ((u>>16)&1u);
  return (u16)(u>>16);
}
__device__ __forceinline__ u32 pk2bf(f32x2 v){
#if defined(__has_builtin) && __has_builtin(__builtin_amdgcn_cvt_pk_bf16_f32)
  auto r = __builtin_amdgcn_cvt_pk_bf16_f32(v.x, v.y);
  u32 u; __builtin_memcpy(&u, &r, 4); return u;
#else
  return ((__float_as_uint(v.x)+0x8000u)>>16) | ((__float_as_uint(v.y)+0x8000u) & 0xffff0000u);
#endif
}
__device__ __forceinline__ f32x2 upk2(u32 d){
  return f32x2{ __uint_as_float(d<<16), __uint_as_float(d & 0xffff0000u) };
}
template<bool F32>
__device__ __forceinline__ float ldv(const void* p, int i){
  if (F32) return ((const float*)p)[i];
  return bf2f(((const u16*)p)[i]);
}
template<bool F32>
__device__ __forceinline__ u16 ldbf(const void* p, int i){
  if (F32) return f2bf(((const float*)p)[i]);
  return ((const u16*)p)[i];
}
__device__ __forceinline__ bf16x8 cat44(bf16x4 lo, bf16x4 hi){
  bf16x8 r = {lo[0],lo[1],lo[2],lo[3],hi[0],hi[1],hi[2],hi[3]};
  return r;
}
__device__ __forceinline__ bf16x8 mk8(u32 a0, u32 a1, u32 a2, u32 a3){
  u32 t[4] = {a0,a1,a2,a3};
  bf16x8 r; __builtin_memcpy(&r, t, 16); return r;
}
__device__ __forceinline__ u32 silu_pk(float za, float zb){
  float ea = __builtin_amdgcn_exp2f(za * -L2E);
  float eb = __builtin_amdgcn_exp2f(zb * -L2E);
  float ra = __builtin_amdgcn_rcpf(1.f + ea);
  float rb = __builtin_amdgcn_rcpf(1.f + eb);
  return pk2bf(f32x2{za*ra, zb*rb});
}

__device__ __forceinline__ int sniff_bf16(const void* tok_emb, int tid){
  int sane = 0;
  if (tid < 64){
    u16 wd = ((const u16*)tok_emb)[tid];
    int e = (wd >> 7) & 0xFF;
    sane = (e >= 100 && e <= 140) ? 1 : 0;
  }
  return (__syncthreads_count(sane) >= 52) ? 1 : 0;
}

// ===== pre-kernel 1: weight fragments (grid 288 x 64) =====
// r13 change: w2 fragments stored with C-quad-pair k-order so the Phase-E
// H^T C-output concatenation is a valid matching B-operand:
//   element j -> hidden = kc*32 + (j>=4 ? 16 : 0) + quad*4 + (j&3)
template<bool F32>
__device__ __forceinline__ void frag_body(const void* wq, const void* wk,
    const void* wv, const void* wo, const void* w1, const void* w2, void* ws)
{
  int t = blockIdx.x;
  int l = t / 72, k = t % 72;
  int lane = threadIdx.x, l16 = lane & 15, quad = lane >> 4;
  bf16x8 v;
  if (k < 8){
    int mat = k >> 1, half = k & 1;
    if (mat == 2){
      // wvo = wv @ wo  (f32 accumulate, single bf16 rounding)
      int col = half*16 + l16;
      #pragma unroll
      for (int j=0;j<8;j++){
        int a = quad*8 + j;
        float acc = 0.f;
        for (int e=0;e<EE;e++)
          acc += ldv<F32>(wv, l*1024 + a*32 + e) * ldv<F32>(wo, l*1024 + e*32 + col);
        v[j] = (short)f2bf(acc);
      }
    } else {
      const void* src = (mat==0)? wq : (mat==1)? wk : wo;
      #pragma unroll
      for (int j=0;j<8;j++)
        v[j] = (short)ldbf<F32>(src, l*1024 + (quad*8+j)*32 + half*16 + l16);
    }
  } else if (k < 40){
    int nt = k - 8;
    #pragma unroll
    for (int j=0;j<8;j++)
      v[j] = (short)ldbf<F32>(w1, l*16384 + (quad*8+j)*512 + nt*16 + l16);
  } else {
    int kc = (k-40)>>1, nh = (k-40)&1;
    #pragma unroll
    for (int j=0;j<8;j++){
      int hh = kc*32 + ((j&4) ? 16 : 0) + quad*4 + (j&3);
      v[j] = (short)ldbf<F32>(w2, l*16384 + hh*32 + nh*16 + l16);
    }
  }
  *(bf16x8*)((char*)ws + WS_FRAG + t*1024 + lane*16) = v;
}

__global__ __launch_bounds__(64) void fmt_frags(
    const void* __restrict__ tok_emb,
    const void* __restrict__ wq, const void* __restrict__ wk,
    const void* __restrict__ wv, const void* __restrict__ wo,
    const void* __restrict__ w1, const void* __restrict__ w2,
    void* __restrict__ ws)
{
  if (sniff_bf16(tok_emb, threadIdx.x)) frag_body<false>(wq,wk,wv,wo,w1,w2,ws);
  else                                  frag_body<true >(wq,wk,wv,wo,w1,w2,ws);
}

// ===== pre-kernel 2: biases / LN / head params =====
template<bool F32>
__device__ __forceinline__ void bias_body(
    const void* bq, const void* bk, const void* bv, const void* wo, const void* bo,
    const void* ln1_g, const void* ln1_b, const void* ln2_g, const void* ln2_b,
    const void* b1, const void* b2,
    const void* lnf_g, const void* lnf_b, const void* wpen, const void* bpen,
    const void* wfan, const void* bfan, const void* wcal, const void* bcal,
    void* ws)
{
  int tid = threadIdx.x, idx = tid & 31, grp = tid >> 5;
  float* BW  = (float*)((char*)ws + WS_BIAS);
  float* BW1 = (float*)((char*)ws + WS_B1);
  float* FW  = (float*)((char*)ws + WS_FIN);
  for (int l=0;l<NTRL;l++){
    float v = 0.f;
    switch(grp){
      case 0: v = ldv<F32>(bq, l*32+idx); break;
      case 1: v = ldv<F32>(bk, l*32+idx); break;
      case 2: {
        float acc = ldv<F32>(bo, l*32+idx);
        for (int e=0;e<EE;e++) acc += ldv<F32>(bv, l*32+e) * ldv<F32>(wo, l*1024 + e*32 + idx);
        v = acc; break;
      }
      case 3: v = ldv<F32>(ln1_g, l*32+idx); break;
      case 4: v = ldv<F32>(ln1_b, l*32+idx); break;
      case 5: v = ldv<F32>(ln2_g, l*32+idx); break;
      case 6: v = ldv<F32>(ln2_b, l*32+idx); break;
      case 7: v = ldv<F32>(b2,   l*32+idx); break;
    }
    BW[l*256 + tid] = v;
  }
  for (int i=tid; i<NTRL*HIDN; i+=256) BW1[i] = ldv<F32>(b1, i);
  if (tid < 32){
    FW[tid]    = ldv<F32>(lnf_g, tid);
    FW[32+tid] = ldv<F32>(lnf_b, tid);
    FW[64+tid] = ldv<F32>(wpen, tid);
  }
  if (tid == 0) FW[96] = ldv<F32>(bpen, 0);
  if (tid < 16){ FW[97+tid] = ldv<F32>(wfan, tid); FW[113+tid] = ldv<F32>(bfan, tid); }
  if (tid < 128) FW[129+tid] = ldv<F32>(wcal, tid);
  if (tid < 8)   FW[257+tid] = ldv<F32>(bcal, tid);
}

__global__ __launch_bounds__(256) void fmt_bias(
    const void* __restrict__ tok_emb,
    const void* __restrict__ bq, const void* __restrict__ bk,
    const void* __restrict__ bv, const void* __restrict__ wo, const void* __restrict__ bo,
    const void* __restrict__ ln1_g, const void* __restrict__ ln1_b,
    const void* __restrict__ ln2_g, const void* __restrict__ ln2_b,
    const void* __restrict__ b1, const void* __restrict__ b2,
    const void* __restrict__ lnf_g, const void* __restrict__ lnf_b,
    const void* __restrict__ wpen, const void* __restrict__ bpen,
    const void* __restrict__ wfan, const void* __restrict__ bfan,
    const void* __restrict__ wcal, const void* __restrict__ bcal,
    void* __restrict__ ws)
{
  if (sniff_bf16(tok_emb, threadIdx.x))
    bias_body<false>(bq,bk,bv,wo,bo,ln1_g,ln1_b,ln2_g,ln2_b,b1,b2,
                     lnf_g,lnf_b,wpen,bpen,wfan,bfan,wcal,bcal,ws);
  else
    bias_body<true >(bq,bk,bv,wo,bo,ln1_g,ln1_b,ln2_g,ln2_b,b1,b2,
                     lnf_g,lnf_b,wpen,bpen,wfan,bfan,wcal,bcal,ws);
}

// ===== main kernel =====
__device__ __forceinline__ void ln_stats(const u16* Xb, float* MS, float* RS, int tid){
  if (tid < SP){
    const u32* row = (const u32*)(Xb + tid*XST);
    f32x2 v[16]; f32x2 s2 = {0.f,0.f};
    #pragma unroll
    for (int i=0;i<16;i++){ f32x2 p = upk2(row[i]); v[i] = p; s2 += p; }
    float m = (s2.x + s2.y) * (1.f/EE);
    f32x2 m2 = {m, m};
    f32x2 var2 = {0.f,0.f};
    #pragma unroll
    for (int i=0;i<16;i++){ f32x2 d = v[i]-m2; var2 += d*d; }
    MS[tid] = m;
    RS[tid] = rsqrtf((var2.x+var2.y)*(1.f/EE) + 1e-5f);
  }
}

__device__ __forceinline__ bf16x8 build_nfrag(const u16* Xb, const float* MS, const float* RS,
                                              int row, int quad, const f32x2* G2, const f32x2* B2){
  const u32* raw = (const u32*)(Xb + row*XST + quad*8);
  f32x2 m2 = { MS[row], MS[row] };
  f32x2 rs2 = { RS[row], RS[row] };
  u32 o[4];
  #pragma unroll
  for (int p=0;p<4;p++){
    f32x2 x = upk2(raw[p]);
    o[p] = pk2bf((x - m2) * rs2 * G2[p] + B2[p]);
  }
  bf16x8 r; __builtin_memcpy(&r, o, 16);
  return r;
}

template<bool F32>
__device__ __forceinline__ void tr_body(
    const int* seq, const int* expid,
    const void* tok_emb, const void* pos_emb,
    const void* ws, void* out, unsigned char* smem)
{
  u16*   Xb   = (u16*)(smem + X_OFF);
  u16*   Kb   = (u16*)(smem + K_OFF);
  u16*   VWTb = (u16*)(smem + VWT_OFF);
  float* MS   = (float*)(smem + MS_OFF);
  float* RS   = (float*)(smem + RS_OFF);
  float* BIAS = (float*)(smem + BIAS_OFF);

  const int tid  = threadIdx.x;
  const int lane = tid & 63, w = tid >> 6;
  const int l16  = lane & 15, quad = lane >> 4;
  const int b    = blockIdx.x;
  const f32x4 Z  = {0.f,0.f,0.f,0.f};

  // ---- embedding + positional (pad rows zeroed) ----
  {
    const int* srow = seq + b*SS;
    for (int i = tid; i < SP*EE; i += 256){
      int s = i >> 5, e = i & 31;
      float val = 0.f;
      if (s < SS){
        int tok = srow[s];
        val = ldv<F32>(tok_emb, tok*EE + e) + ldv<F32>(pos_emb, s*EE + e);
      }
      Xb[s*XST + e] = f2bf(val);
    }
  }
  __syncthreads();

  const float qce = 0.2550546813f;  // (1/sqrt(32)) * log2(e)
  const f32x4 qce4 = {qce, qce, qce, qce};

  for (int l = 0; l < NTRL; ++l){
    const char* wsl = (const char*)ws + WS_FRAG + l*73728;
    // ===== Phase A =====
    bf16x8 bwq0 = *(const bf16x8*)(wsl + 0*1024 + lane*16);
    bf16x8 bwq1 = *(const bf16x8*)(wsl + 1*1024 + lane*16);
    bf16x8 bwk0 = *(const bf16x8*)(wsl + 2*1024 + lane*16);
    bf16x8 bwk1 = *(const bf16x8*)(wsl + 3*1024 + lane*16);
    bf16x8 bwv0 = *(const bf16x8*)(wsl + 4*1024 + lane*16);  // wvo halves
    bf16x8 bwv1 = *(const bf16x8*)(wsl + 5*1024 + lane*16);
    {
      const float* BW = (const float*)((const char*)ws + WS_BIAS) + l*256;
      BIAS[tid] = BW[tid];
    }
    for (int i = tid; i < 32*16; i += 256)
      VWTb[(i>>4)*VWST + 208 + (i&15)] = 0;
    ln_stats(Xb, MS, RS, tid);
    __syncthreads();

    // ===== Phase B: K, VW (= N@wvo) to LDS; Q^T packed in-register =====
    // Q^T = MF(bwq, an): C rows = e-out (quad*4+r), cols = query (l16).
    // aq[t] B-operand k-order: j<4 -> e=quad*4+j, j>=4 -> e=16+quad*4+(j-4);
    // Phase C reads K with the matching cat44 half split.
    bf16x8 aq[4];
    {
      f32x2 G2[4], B2[4];
      #pragma unroll
      for (int p=0;p<4;p++){
        G2[p] = f32x2{BIAS[96+quad*8+2*p], BIAS[96+quad*8+2*p+1]};
        B2[p] = f32x2{BIAS[128+quad*8+2*p], BIAS[128+quad*8+2*p+1]};
      }
      f32x2 bkb2 = {BIAS[32+l16], BIAS[48+l16]};
      f32x4 bq0 = *(const f32x4*)(BIAS + quad*4);
      f32x4 bq1 = *(const f32x4*)(BIAS + 16 + quad*4);
      #pragma unroll
      for (int t=0;t<4;t++){
        int m = w + 4*t;
        if (m < NMT){
          int m16 = m*16;
          bf16x8 an = build_nfrag(Xb, MS, RS, m16+l16, quad, G2, B2);
          f32x4 ck0 = MF(an, bwk0, Z), ck1 = MF(an, bwk1, Z);
          #pragma unroll
          for (int r=0;r<4;r++){
            int row = m16 + quad*4 + r;
            u32 pk = pk2bf(f32x2{ck0[r], ck1[r]} + bkb2);
            Kb[row*XST + l16]      = (u16)pk;
            Kb[row*XST + 16 + l16] = (u16)(pk>>16);
          }
          f32x4 cw0 = MF(an, bwv0, Z), cw1 = MF(an, bwv1, Z);
          #pragma unroll
          for (int r=0;r<4;r++){
            u32 pk = pk2bf(f32x2{cw0[r], cw1[r]});
            VWTb[l16*VWST      + m16 + quad*4 + r] = (u16)pk;
            VWTb[(16+l16)*VWST + m16 + quad*4 + r] = (u16)(pk>>16);
          }
          f32x4 cq0 = MF(bwq0, an, Z), cq1 = MF(bwq1, an, Z);
          f32x4 z0 = (cq0 + bq0) * qce4;
          f32x4 z1 = (cq1 + bq1) * qce4;
          aq[t] = mk8(pk2bf(f32x2{z0[0], z0[1]}), pk2bf(f32x2{z0[2], z0[3]}),
                      pk2bf(f32x2{z1[0], z1[1]}), pk2bf(f32x2{z1[2], z1[3]}));
        }
      }
    }
    __syncthreads();

    // ===== Phase C: attention via S^T (no P LDS round trip) =====
    {
      const u16* vbase0 = VWTb + l16*VWST;
      const u16* vbase1 = VWTb + (16+l16)*VWST;
      f32x4 ob0 = *(const f32x4*)(BIAS + 64 + quad*4);       // bv@wo+bo, e=quad*4..+3
      f32x4 ob1 = *(const f32x4*)(BIAS + 80 + quad*4);       // e=16+quad*4..+3
      #pragma unroll
      for (int t=0;t<4;t++){
        int m = w + 4*t;
        if (m < NMT){
          int m16 = m*16;
          // S^T tiles: rows = keys (quad*4+r), cols = queries (l16)
          u32 pbw[13][2];
          float part = 0.f;
          #pragma unroll
          for (int kt=0; kt<13; kt++){
            const u16* krow = Kb + (kt*16+l16)*XST;
            bf16x8 kb8 = cat44(*(const bf16x4*)(krow + quad*4),
                               *(const bf16x4*)(krow + 16 + quad*4));
            f32x4 St = MF(kb8, aq[t], Z);      // K . Q^T = S^T
            float e0 = __builtin_amdgcn_exp2f(St[0]);
            float e1 = __builtin_amdgcn_exp2f(St[1]);
            float e2 = __builtin_amdgcn_exp2f(St[2]);
            float e3 = __builtin_amdgcn_exp2f(St[3]);
            if (kt == 12){                      // keys 201..207: local idx >= 9
              int kb = quad*4;
              if (kb+0 >= 9) e0 = 0.f;
              if (kb+1 >= 9) e1 = 0.f;
              if (kb+2 >= 9) e2 = 0.f;
              if (kb+3 >= 9) e3 = 0.f;
            }
            part += (e0+e1)+(e2+e3);
            pbw[kt][0] = pk2bf(f32x2{e0,e1});
            pbw[kt][1] = pk2bf(f32x2{e2,e3});
          }
          part += __shfl_xor(part, 16);
          part += __shfl_xor(part, 32);
          float inv = __builtin_amdgcn_rcpf(part);   // per query l16

          // PV: O^T = VW^T . P^T, keys paired 2 tiles per K=32 MFMA
          f32x4 o0 = Z, o1 = Z;
          #pragma unroll
          for (int c=0;c<6;c++){
            bf16x4 a0l = *(const bf16x4*)(vbase0 + c*32 + quad*4);
            bf16x4 a0h = *(const bf16x4*)(vbase0 + c*32 + 16 + quad*4);
            bf16x4 a1l = *(const bf16x4*)(vbase1 + c*32 + quad*4);
            bf16x4 a1h = *(const bf16x4*)(vbase1 + c*32 + 16 + quad*4);
            bf16x8 B8 = mk8(pbw[2*c][0], pbw[2*c][1], pbw[2*c+1][0], pbw[2*c+1][1]);
            o0 = MF(cat44(a0l, a0h), B8, o0);
            o1 = MF(cat44(a1l, a1h), B8, o1);
          }
          {
            // tail: tile 12 + zeroed pad (VWT cols 208.. are zeroed; B upper = 0)
            bf16x4 a0l = *(const bf16x4*)(vbase0 + 192 + quad*4);
            bf16x4 a0h = *(const bf16x4*)(vbase0 + 208 + quad*4);
            bf16x4 a1l = *(const bf16x4*)(vbase1 + 192 + quad*4);
            bf16x4 a1h = *(const bf16x4*)(vbase1 + 208 + quad*4);
            bf16x8 B8 = mk8(pbw[12][0], pbw[12][1], 0u, 0u);
            o0 = MF(cat44(a0l, a0h), B8, o0);
            o1 = MF(cat44(a1l, a1h), B8, o1);
          }

          // X[row=m16+l16][cols quad*4..+3 and 16+quad*4..+3] += inv*O^T + ob
          u32* xr = (u32*)(Xb + (m16+l16)*XST);
          {
            u32 d0 = xr[quad*2], d1 = xr[quad*2+1];
            f32x2 r01 = f32x2{o0[0],o0[1]} * inv + (upk2(d0) + f32x2{ob0[0],ob0[1]});
            f32x2 r23 = f32x2{o0[2],o0[3]} * inv + (upk2(d1) + f32x2{ob0[2],ob0[3]});
            xr[quad*2]   = pk2bf(r01);
            xr[quad*2+1] = pk2bf(r23);
            u32 d2 = xr[8+quad*2], d3 = xr[8+quad*2+1];
            f32x2 s01 = f32x2{o1[0],o1[1]} * inv + (upk2(d2) + f32x2{ob1[0],ob1[1]});
            f32x2 s23 = f32x2{o1[2],o1[3]} * inv + (upk2(d3) + f32x2{ob1[2],ob1[3]});
            xr[8+quad*2]   = pk2bf(s01);
            xr[8+quad*2+1] = pk2bf(s23);
          }
        }
      }
    }
    __syncthreads();

    // ===== Phase D: LN2 stats =====
    ln_stats(Xb, MS, RS, tid);
    __syncthreads();

    // ===== Phase E: MLP, register-resident H via operand swap =====
    // H^T tile = MF(w1frag-as-A, anc-as-B): C rows = hidden (quad*4+r),
    // cols = seq (l16). silu in-register; two tiles pack into the K=32
    // B-operand of O^T = MF(w2frag, H8). No LDS scratch, no barriers.
    {
      f32x2 G2[4], B2[4];
      #pragma unroll
      for (int p=0;p<4;p++){
        G2[p] = f32x2{BIAS[160+quad*8+2*p], BIAS[160+quad*8+2*p+1]};
        B2[p] = f32x2{BIAS[192+quad*8+2*p], BIAS[192+quad*8+2*p+1]};
      }
      bf16x8 anc[4];
      #pragma unroll
      for (int t=0;t<4;t++){
        int m = w + 4*t;
        if (m < NMT) anc[t] = build_nfrag(Xb, MS, RS, m*16+l16, quad, G2, B2);
      }
      f32x4 oacc[4][2];
      #pragma unroll
      for (int t=0;t<4;t++){ oacc[t][0] = Z; oacc[t][1] = Z; }
      const char* w1f = wsl + 8*1024;
      const char* w2f = wsl + 40*1024;
      const float* BW1 = (const float*)((const char*)ws + WS_B1) + l*HIDN;

      for (int hp = 0; hp < 16; ++hp){
        bf16x8 a1lo = *(const bf16x8*)(w1f + (2*hp  )*1024 + lane*16);
        bf16x8 a1hi = *(const bf16x8*)(w1f + (2*hp+1)*1024 + lane*16);
        bf16x8 a2e0 = *(const bf16x8*)(w2f + (hp*2  )*1024 + lane*16);
        bf16x8 a2e1 = *(const bf16x8*)(w2f + (hp*2+1)*1024 + lane*16);
        f32x4 b1q0 = *(const f32x4*)(BW1 + hp*32      + quad*4);
        f32x4 b1q1 = *(const f32x4*)(BW1 + hp*32 + 16 + quad*4);
        #pragma unroll
        for (int t=0;t<4;t++){
          int m = w + 4*t;
          if (m < NMT){
            f32x4 z0 = MF(a1lo, anc[t], Z) + b1q0;
            f32x4 z1 = MF(a1hi, anc[t], Z) + b1q1;
            bf16x8 H8 = mk8(silu_pk(z0[0], z0[1]), silu_pk(z0[2], z0[3]),
                            silu_pk(z1[0], z1[1]), silu_pk(z1[2], z1[3]));
            oacc[t][0] = MF(a2e0, H8, oacc[t][0]);
            oacc[t][1] = MF(a2e1, H8, oacc[t][1]);
          }
        }
      }

      // O^T C-layout: rows = e (quad*4+r), cols = seq (l16) — Phase-C-style RMW
      f32x4 b2q0 = *(const f32x4*)(BIAS + 224 + quad*4);
      f32x4 b2q1 = *(const f32x4*)(BIAS + 240 + quad*4);
      #pragma unroll
      for (int t=0;t<4;t++){
        int m = w + 4*t;
        if (m < NMT){
          u32* xr = (u32*)(Xb + (m*16 + l16)*XST);
          u32 d0 = xr[quad*2], d1 = xr[quad*2+1];
          f32x2 r01 = f32x2{oacc[t][0][0], oacc[t][0][1]} + (upk2(d0) + f32x2{b2q0[0], b2q0[1]});
          f32x2 r23 = f32x2{oacc[t][0][2], oacc[t][0][3]} + (upk2(d1) + f32x2{b2q0[2], b2q0[3]});
          xr[quad*2]   = pk2bf(r01);
          xr[quad*2+1] = pk2bf(r23);
          u32 d2 = xr[8+quad*2], d3 = xr[8+quad*2+1];
          f32x2 s01 = f32x2{oacc[t][1][0], oacc[t][1][1]} + (upk2(d2) + f32x2{b2q1[0], b2q1[1]});
          f32x2 s23 = f32x2{oacc[t][1][2], oacc[t][1][3]} + (upk2(d3) + f32x2{b2q1[2], b2q1[3]});
          xr[8+quad*2]   = pk2bf(s01);
          xr[8+quad*2+1] = pk2bf(s23);
        }
      }
    }
    __syncthreads();
  }

  // ===== final head =====
  const float* FW = (const float*)((const char*)ws + WS_FIN);
  if (tid < 32){
    BIAS[tid]    = FW[tid];
    BIAS[32+tid] = FW[32+tid];
    BIAS[64+tid] = FW[64+tid];
  }
  __syncthreads();
  float part = 0.f;
  if (tid < SS){
    const u32* row = (const u32*)(Xb + tid*XST);
    f32x2 v[16]; f32x2 s2 = {0.f,0.f};
    #pragma unroll
    for (int i=0;i<16;i++){ f32x2 p = upk2(row[i]); v[i] = p; s2 += p; }
    float m = (s2.x+s2.y) * (1.f/EE);
    f32x2 m2 = {m,m};
    f32x2 var2 = {0.f,0.f};
    #pragma unroll
    for (int i=0;i<16;i++){ f32x2 d = v[i]-m2; var2 += d*d; }
    float rs = rsqrtf((var2.x+var2.y)*(1.f/EE) + 1e-5f);
    f32x2 rs2 = {rs, rs};
    f32x2 dot2 = {0.f,0.f};
    #pragma unroll
    for (int i=0;i<16;i++){
      f32x2 g  = {BIAS[2*i], BIAS[2*i+1]};
      f32x2 bb = {BIAS[32+2*i], BIAS[33+2*i]};
      f32x2 wp = {BIAS[64+2*i], BIAS[65+2*i]};
      dot2 += ((v[i]-m2)*rs2*g + bb) * wp;
    }
    part = dot2.x + dot2.y + FW[96];
  }
  #pragma unroll
  for (int off=32; off; off>>=1) part += __shfl_xor(part, off);
  float* REDF = (float*)(smem + QS_OFF);
  __syncthreads();
  if (lane == 0) REDF[w] = part;
  __syncthreads();
  if (tid == 0){
    float u = REDF[0] + REDF[1] + REDF[2] + REDF[3];
    int ex = expid[b];
    float corr = FW[257+ex];
    #pragma unroll
    for (int c = 0; c < CWN; ++c){
      float pre = u * FW[97+c] + FW[113+c];
      pre = pre > 0.f ? pre : (__expf(pre) - 1.f);
      corr += pre * FW[129 + ex*CWN + c];
    }
    float res = corr + u;
    if (F32) ((float*)out)[b] = res;
    else     ((u16*)out)[b]  = f2bf(res);
  }
}

__global__ __launch_bounds__(256, 3) void tr_kernel(
    const int* __restrict__ seq, const int* __restrict__ expid,
    const void* __restrict__ tok_emb, const void* __restrict__ pos_emb,
    const void* __restrict__ ws, void* __restrict__ out)
{
  __shared__ __align__(16) unsigned char smem[SMEM_SZ];
  if (sniff_bf16(tok_emb, threadIdx.x))
    tr_body<false>(seq, expid, tok_emb, pos_emb, ws, out, smem);
  else
    tr_body<true >(seq, expid, tok_emb, pos_emb, ws, out, smem);
}

extern "C" void kernel_launch(void* const* d_in, const int* in_sizes, int n_in,
                              void* d_out, int out_size, void* d_ws, size_t ws_size,
                              hipStream_t stream)
{
  (void)in_sizes; (void)n_in; (void)ws_size; (void)out_size;
  const void* tok_emb = d_in[2];
  fmt_frags<<<dim3(288), dim3(64), 0, stream>>>(
      tok_emb, d_in[6], d_in[7], d_in[8], d_in[12], d_in[16], d_in[18], d_ws);
  fmt_bias<<<dim3(1), dim3(256), 0, stream>>>(
      tok_emb, d_in[9], d_in[10], d_in[11], d_in[12], d_in[13],
      d_in[4], d_in[5], d_in[14], d_in[15], d_in[17], d_in[19],
      d_in[20], d_in[21], d_in[22], d_in[23],
      d_in[24], d_in[25], d_in[26], d_in[27], d_ws);
  tr_kernel<<<dim3(BB), dim3(256), 0, stream>>>(
      (const int*)d_in[0], (const int*)d_in[1], tok_emb, d_in[3], d_ws, d_out);
}

// Round 2
// 881.978 us; speedup vs baseline: 1.0792x; 1.0792x over previous
//
#include <hip/hip_runtime.h>

// TrPredictor round 14 = r13 structure + VALU de-scalarization.
// r13 post-mortem: register-resident MLP/Q removed DS-pipe work (conflicts
// 1.36e7 -> 0) but ADDED ~22% VALU-issue time via scalar silu arithmetic,
// post-MFMA bias adds, and packing moves -- on the bottleneck pipe.
// r14 keeps the structure and cuts VALU issue slots:
//  - packed silu (f32x2 -> v_pk_*_f32), exact same math sequence as r12
//  - biases folded into MFMA C-operand (W1, Q, K) -- exact, zero VALU
//  - one-pass ln_stats (sum + sumsq via pk_fma)
//  - packed softmax-denominator accumulation
//  - dead QS region dropped; VWT zero-fill dropped (PV tail dups A-lo,
//    B-hi is zero so product unchanged)

#define SS   201
#define SP   208
#define NMT  13
#define EE   32
#define HIDN 512
#define NTRL 4
#define CWN  16
#define BB   4096
#define XST  36
#define VWST 228

#define X_OFF    0
#define K_OFF    14976
#define VWT_OFF  29952   // VW^T [32][228]
#define MS_OFF   44544   // also final-head reduction scratch
#define RS_OFF   45376
#define BIAS_OFF 46208
#define SMEM_SZ  47232

#define WS_FRAG  0        // 288 tiles x 1024 B; per layer: 0,1=q 2,3=k 4,5=wvo 6,7=unused
#define WS_BIAS  294912
#define WS_B1    299008
#define WS_FIN   307200
#define L2E      1.4426950408889634f

typedef unsigned short u16;
typedef unsigned int   u32;
typedef short bf16x4 __attribute__((ext_vector_type(4)));
typedef short bf16x8 __attribute__((ext_vector_type(8)));
typedef float f32x4  __attribute__((ext_vector_type(4)));
typedef float f32x2  __attribute__((ext_vector_type(2)));

__device__ __forceinline__ f32x4 MF(bf16x8 a, bf16x8 b, f32x4 c){
  return __builtin_amdgcn_mfma_f32_16x16x32_bf16(a, b, c, 0, 0, 0);
}
__device__ __forceinline__ float bf2f(u16 u){ return __uint_as_float(((u32)u)<<16); }
__device__ __forceinline__ u16 f2bf(float f){            // exact RNE (cold paths)
  u32 u = __float_as_uint(f);
  u += 0x7fffu + ((u>>16)&1u);
  return (u16)(u>>16);
}
__device__ __forceinline__ u32 pk2bf(f32x2 v){
#if defined(__has_builtin) && __has_builtin(__builtin_amdgcn_cvt_pk_bf16_f32)
  auto r = __builtin_amdgcn_cvt_pk_bf16_f32(v.x, v.y);
  u32 u; __builtin_memcpy(&u, &r, 4); return u;
#else
  return ((__float_as_uint(v.x)+0x8000u)>>16) | ((__float_as_uint(v.y)+0x8000u) & 0xffff0000u);
#endif
}
__device__ __forceinline__ f32x2 upk2(u32 d){
  return f32x2{ __uint_as_float(d<<16), __uint_as_float(d & 0xffff0000u) };
}
template<bool F32>
__device__ __forceinline__ float ldv(const void* p, int i){
  if (F32) return ((const float*)p)[i];
  return bf2f(((const u16*)p)[i]);
}
template<bool F32>
__device__ __forceinline__ u16 ldbf(const void* p, int i){
  if (F32) return f2bf(((const float*)p)[i]);
  return ((const u16*)p)[i];
}
__device__ __forceinline__ bf16x8 cat44(bf16x4 lo, bf16x4 hi){
  bf16x8 r = {lo[0],lo[1],lo[2],lo[3],hi[0],hi[1],hi[2],hi[3]};
  return r;
}
__device__ __forceinline__ bf16x8 mk8(u32 a0, u32 a1, u32 a2, u32 a3){
  u32 t[4] = {a0,a1,a2,a3};
  bf16x8 r; __builtin_memcpy(&r, t, 16); return r;
}
// packed silu -> bf16 pair; all arith is f32x2 (v_pk_*_f32), trans scalar
__device__ __forceinline__ u32 spk(f32x2 z){
  const f32x2 nl2e2 = {-L2E, -L2E};
  const f32x2 one2  = {1.f, 1.f};
  f32x2 a = z * nl2e2;
  f32x2 e = { __builtin_amdgcn_exp2f(a.x), __builtin_amdgcn_exp2f(a.y) };
  f32x2 d = one2 + e;
  f32x2 rc = { __builtin_amdgcn_rcpf(d.x), __builtin_amdgcn_rcpf(d.y) };
  f32x2 s = z * rc;
  return pk2bf(s);
}

__device__ __forceinline__ int sniff_bf16(const void* tok_emb, int tid){
  int sane = 0;
  if (tid < 64){
    u16 wd = ((const u16*)tok_emb)[tid];
    int e = (wd >> 7) & 0xFF;
    sane = (e >= 100 && e <= 140) ? 1 : 0;
  }
  return (__syncthreads_count(sane) >= 52) ? 1 : 0;
}

// ===== pre-kernel 1: weight fragments (grid 288 x 64) =====
// w2 fragments stored with C-quad-pair k-order so the Phase-E H^T C-output
// concatenation is a valid matching B-operand:
//   element j -> hidden = kc*32 + (j>=4 ? 16 : 0) + quad*4 + (j&3)
template<bool F32>
__device__ __forceinline__ void frag_body(const void* wq, const void* wk,
    const void* wv, const void* wo, const void* w1, const void* w2, void* ws)
{
  int t = blockIdx.x;
  int l = t / 72, k = t % 72;
  int lane = threadIdx.x, l16 = lane & 15, quad = lane >> 4;
  bf16x8 v;
  if (k < 8){
    int mat = k >> 1, half = k & 1;
    if (mat == 2){
      // wvo = wv @ wo  (f32 accumulate, single bf16 rounding)
      int col = half*16 + l16;
      #pragma unroll
      for (int j=0;j<8;j++){
        int a = quad*8 + j;
        float acc = 0.f;
        for (int e=0;e<EE;e++)
          acc += ldv<F32>(wv, l*1024 + a*32 + e) * ldv<F32>(wo, l*1024 + e*32 + col);
        v[j] = (short)f2bf(acc);
      }
    } else {
      const void* src = (mat==0)? wq : (mat==1)? wk : wo;
      #pragma unroll
      for (int j=0;j<8;j++)
        v[j] = (short)ldbf<F32>(src, l*1024 + (quad*8+j)*32 + half*16 + l16);
    }
  } else if (k < 40){
    int nt = k - 8;
    #pragma unroll
    for (int j=0;j<8;j++)
      v[j] = (short)ldbf<F32>(w1, l*16384 + (quad*8+j)*512 + nt*16 + l16);
  } else {
    int kc = (k-40)>>1, nh = (k-40)&1;
    #pragma unroll
    for (int j=0;j<8;j++){
      int hh = kc*32 + ((j&4) ? 16 : 0) + quad*4 + (j&3);
      v[j] = (short)ldbf<F32>(w2, l*16384 + hh*32 + nh*16 + l16);
    }
  }
  *(bf16x8*)((char*)ws + WS_FRAG + t*1024 + lane*16) = v;
}

__global__ __launch_bounds__(64) void fmt_frags(
    const void* __restrict__ tok_emb,
    const void* __restrict__ wq, const void* __restrict__ wk,
    const void* __restrict__ wv, const void* __restrict__ wo,
    const void* __restrict__ w1, const void* __restrict__ w2,
    void* __restrict__ ws)
{
  if (sniff_bf16(tok_emb, threadIdx.x)) frag_body<false>(wq,wk,wv,wo,w1,w2,ws);
  else                                  frag_body<true >(wq,wk,wv,wo,w1,w2,ws);
}

// ===== pre-kernel 2: biases / LN / head params =====
template<bool F32>
__device__ __forceinline__ void bias_body(
    const void* bq, const void* bk, const void* bv, const void* wo, const void* bo,
    const void* ln1_g, const void* ln1_b, const void* ln2_g, const void* ln2_b,
    const void* b1, const void* b2,
    const void* lnf_g, const void* lnf_b, const void* wpen, const void* bpen,
    const void* wfan, const void* bfan, const void* wcal, const void* bcal,
    void* ws)
{
  int tid = threadIdx.x, idx = tid & 31, grp = tid >> 5;
  float* BW  = (float*)((char*)ws + WS_BIAS);
  float* BW1 = (float*)((char*)ws + WS_B1);
  float* FW  = (float*)((char*)ws + WS_FIN);
  for (int l=0;l<NTRL;l++){
    float v = 0.f;
    switch(grp){
      case 0: v = ldv<F32>(bq, l*32+idx); break;
      case 1: v = ldv<F32>(bk, l*32+idx); break;
      case 2: {
        float acc = ldv<F32>(bo, l*32+idx);
        for (int e=0;e<EE;e++) acc += ldv<F32>(bv, l*32+e) * ldv<F32>(wo, l*1024 + e*32 + idx);
        v = acc; break;
      }
      case 3: v = ldv<F32>(ln1_g, l*32+idx); break;
      case 4: v = ldv<F32>(ln1_b, l*32+idx); break;
      case 5: v = ldv<F32>(ln2_g, l*32+idx); break;
      case 6: v = ldv<F32>(ln2_b, l*32+idx); break;
      case 7: v = ldv<F32>(b2,   l*32+idx); break;
    }
    BW[l*256 + tid] = v;
  }
  for (int i=tid; i<NTRL*HIDN; i+=256) BW1[i] = ldv<F32>(b1, i);
  if (tid < 32){
    FW[tid]    = ldv<F32>(lnf_g, tid);
    FW[32+tid] = ldv<F32>(lnf_b, tid);
    FW[64+tid] = ldv<F32>(wpen, tid);
  }
  if (tid == 0) FW[96] = ldv<F32>(bpen, 0);
  if (tid < 16){ FW[97+tid] = ldv<F32>(wfan, tid); FW[113+tid] = ldv<F32>(bfan, tid); }
  if (tid < 128) FW[129+tid] = ldv<F32>(wcal, tid);
  if (tid < 8)   FW[257+tid] = ldv<F32>(bcal, tid);
}

__global__ __launch_bounds__(256) void fmt_bias(
    const void* __restrict__ tok_emb,
    const void* __restrict__ bq, const void* __restrict__ bk,
    const void* __restrict__ bv, const void* __restrict__ wo, const void* __restrict__ bo,
    const void* __restrict__ ln1_g, const void* __restrict__ ln1_b,
    const void* __restrict__ ln2_g, const void* __restrict__ ln2_b,
    const void* __restrict__ b1, const void* __restrict__ b2,
    const void* __restrict__ lnf_g, const void* __restrict__ lnf_b,
    const void* __restrict__ wpen, const void* __restrict__ bpen,
    const void* __restrict__ wfan, const void* __restrict__ bfan,
    const void* __restrict__ wcal, const void* __restrict__ bcal,
    void* __restrict__ ws)
{
  if (sniff_bf16(tok_emb, threadIdx.x))
    bias_body<false>(bq,bk,bv,wo,bo,ln1_g,ln1_b,ln2_g,ln2_b,b1,b2,
                     lnf_g,lnf_b,wpen,bpen,wfan,bfan,wcal,bcal,ws);
  else
    bias_body<true >(bq,bk,bv,wo,bo,ln1_g,ln1_b,ln2_g,ln2_b,b1,b2,
                     lnf_g,lnf_b,wpen,bpen,wfan,bfan,wcal,bcal,ws);
}

// ===== main kernel =====
// one-pass LN stats: var = E[x^2] - m^2 (pk_fma accumulate)
__device__ __forceinline__ void ln_stats(const u16* Xb, float* MS, float* RS, int tid){
  if (tid < SP){
    const u32* row = (const u32*)(Xb + tid*XST);
    f32x2 s2 = {0.f,0.f}, q2 = {0.f,0.f};
    #pragma unroll
    for (int i=0;i<16;i++){ f32x2 p = upk2(row[i]); s2 += p; q2 += p*p; }
    float m = (s2.x + s2.y) * (1.f/EE);
    float v = (q2.x + q2.y) * (1.f/EE) - m*m;
    MS[tid] = m;
    RS[tid] = rsqrtf(v + 1e-5f);
  }
}

__device__ __forceinline__ bf16x8 build_nfrag(const u16* Xb, const float* MS, const float* RS,
                                              int row, int quad, const f32x2* G2, const f32x2* B2){
  const u32* raw = (const u32*)(Xb + row*XST + quad*8);
  f32x2 m2 = { MS[row], MS[row] };
  f32x2 rs2 = { RS[row], RS[row] };
  u32 o[4];
  #pragma unroll
  for (int p=0;p<4;p++){
    f32x2 x = upk2(raw[p]);
    o[p] = pk2bf((x - m2) * rs2 * G2[p] + B2[p]);
  }
  bf16x8 r; __builtin_memcpy(&r, o, 16);
  return r;
}

template<bool F32>
__device__ __forceinline__ void tr_body(
    const int* seq, const int* expid,
    const void* tok_emb, const void* pos_emb,
    const void* ws, void* out, unsigned char* smem)
{
  u16*   Xb   = (u16*)(smem + X_OFF);
  u16*   Kb   = (u16*)(smem + K_OFF);
  u16*   VWTb = (u16*)(smem + VWT_OFF);
  float* MS   = (float*)(smem + MS_OFF);
  float* RS   = (float*)(smem + RS_OFF);
  float* BIAS = (float*)(smem + BIAS_OFF);

  const int tid  = threadIdx.x;
  const int lane = tid & 63, w = tid >> 6;
  const int l16  = lane & 15, quad = lane >> 4;
  const int b    = blockIdx.x;
  const f32x4 Z  = {0.f,0.f,0.f,0.f};

  // ---- embedding + positional (pad rows zeroed) ----
  {
    const int* srow = seq + b*SS;
    for (int i = tid; i < SP*EE; i += 256){
      int s = i >> 5, e = i & 31;
      float val = 0.f;
      if (s < SS){
        int tok = srow[s];
        val = ldv<F32>(tok_emb, tok*EE + e) + ldv<F32>(pos_emb, s*EE + e);
      }
      Xb[s*XST + e] = f2bf(val);
    }
  }
  __syncthreads();

  const float qce = 0.2550546813f;  // (1/sqrt(32)) * log2(e)
  const f32x2 qce2 = {qce, qce};

  for (int l = 0; l < NTRL; ++l){
    const char* wsl = (const char*)ws + WS_FRAG + l*73728;
    // ===== Phase A =====
    bf16x8 bwq0 = *(const bf16x8*)(wsl + 0*1024 + lane*16);
    bf16x8 bwq1 = *(const bf16x8*)(wsl + 1*1024 + lane*16);
    bf16x8 bwk0 = *(const bf16x8*)(wsl + 2*1024 + lane*16);
    bf16x8 bwk1 = *(const bf16x8*)(wsl + 3*1024 + lane*16);
    bf16x8 bwv0 = *(const bf16x8*)(wsl + 4*1024 + lane*16);  // wvo halves
    bf16x8 bwv1 = *(const bf16x8*)(wsl + 5*1024 + lane*16);
    {
      const float* BW = (const float*)((const char*)ws + WS_BIAS) + l*256;
      BIAS[tid] = BW[tid];
    }
    ln_stats(Xb, MS, RS, tid);
    __syncthreads();

    // ===== Phase B: K, VW (= N@wvo) to LDS; Q^T packed in-register =====
    // Q^T = MF(bwq, an, C=bq): C rows = e-out (quad*4+r), cols = query (l16).
    // K bias folded as splat C. All biases exact (MFMA C-operand).
    bf16x8 aq[4];
    {
      f32x2 G2[4], B2[4];
      #pragma unroll
      for (int p=0;p<4;p++){
        G2[p] = f32x2{BIAS[96+quad*8+2*p], BIAS[96+quad*8+2*p+1]};
        B2[p] = f32x2{BIAS[128+quad*8+2*p], BIAS[128+quad*8+2*p+1]};
      }
      f32x4 bq0 = *(const f32x4*)(BIAS + quad*4);
      f32x4 bq1 = *(const f32x4*)(BIAS + 16 + quad*4);
      float bk0s = BIAS[32+l16], bk1s = BIAS[48+l16];
      f32x4 kc0 = {bk0s,bk0s,bk0s,bk0s};
      f32x4 kc1 = {bk1s,bk1s,bk1s,bk1s};
      #pragma unroll
      for (int t=0;t<4;t++){
        int m = w + 4*t;
        if (m < NMT){
          int m16 = m*16;
          bf16x8 an = build_nfrag(Xb, MS, RS, m16+l16, quad, G2, B2);
          f32x4 ck0 = MF(an, bwk0, kc0), ck1 = MF(an, bwk1, kc1);
          #pragma unroll
          for (int r=0;r<4;r++){
            int row = m16 + quad*4 + r;
            u32 pk = pk2bf(f32x2{ck0[r], ck1[r]});
            Kb[row*XST + l16]      = (u16)pk;
            Kb[row*XST + 16 + l16] = (u16)(pk>>16);
          }
          f32x4 cw0 = MF(an, bwv0, Z), cw1 = MF(an, bwv1, Z);
          #pragma unroll
          for (int r=0;r<4;r++){
            u32 pk = pk2bf(f32x2{cw0[r], cw1[r]});
            VWTb[l16*VWST      + m16 + quad*4 + r] = (u16)pk;
            VWTb[(16+l16)*VWST + m16 + quad*4 + r] = (u16)(pk>>16);
          }
          f32x4 cq0 = MF(bwq0, an, bq0), cq1 = MF(bwq1, an, bq1);
          aq[t] = mk8(pk2bf(f32x2{cq0[0],cq0[1]}*qce2), pk2bf(f32x2{cq0[2],cq0[3]}*qce2),
                      pk2bf(f32x2{cq1[0],cq1[1]}*qce2), pk2bf(f32x2{cq1[2],cq1[3]}*qce2));
        }
      }
    }
    __syncthreads();

    // ===== Phase C: attention via S^T (no P LDS round trip) =====
    {
      const u16* vbase0 = VWTb + l16*VWST;
      const u16* vbase1 = VWTb + (16+l16)*VWST;
      f32x4 ob0 = *(const f32x4*)(BIAS + 64 + quad*4);       // bv@wo+bo, e=quad*4..+3
      f32x4 ob1 = *(const f32x4*)(BIAS + 80 + quad*4);       // e=16+quad*4..+3
      #pragma unroll
      for (int t=0;t<4;t++){
        int m = w + 4*t;
        if (m < NMT){
          int m16 = m*16;
          // S^T tiles: rows = keys (quad*4+r), cols = queries (l16)
          u32 pbw[13][2];
          f32x2 pacc = {0.f, 0.f};
          #pragma unroll
          for (int kt=0; kt<13; kt++){
            const u16* krow = Kb + (kt*16+l16)*XST;
            bf16x8 kb8 = cat44(*(const bf16x4*)(krow + quad*4),
                               *(const bf16x4*)(krow + 16 + quad*4));
            f32x4 St = MF(kb8, aq[t], Z);      // K . Q^T = S^T
            f32x2 ea = { __builtin_amdgcn_exp2f(St[0]), __builtin_amdgcn_exp2f(St[1]) };
            f32x2 eb = { __builtin_amdgcn_exp2f(St[2]), __builtin_amdgcn_exp2f(St[3]) };
            if (kt == 12){                      // keys 201..207: local idx >= 9
              int kb = quad*4;
              if (kb+0 >= 9) ea.x = 0.f;
              if (kb+1 >= 9) ea.y = 0.f;
              if (kb+2 >= 9) eb.x = 0.f;
              if (kb+3 >= 9) eb.y = 0.f;
            }
            pacc += ea + eb;
            pbw[kt][0] = pk2bf(ea);
            pbw[kt][1] = pk2bf(eb);
          }
          float part = pacc.x + pacc.y;
          part += __shfl_xor(part, 16);
          part += __shfl_xor(part, 32);
          float inv = __builtin_amdgcn_rcpf(part);   // per query l16

          // PV: O^T = VW^T . P^T, keys paired 2 tiles per K=32 MFMA
          f32x4 o0 = Z, o1 = Z;
          #pragma unroll
          for (int c=0;c<6;c++){
            bf16x4 a0l = *(const bf16x4*)(vbase0 + c*32 + quad*4);
            bf16x4 a0h = *(const bf16x4*)(vbase0 + c*32 + 16 + quad*4);
            bf16x4 a1l = *(const bf16x4*)(vbase1 + c*32 + quad*4);
            bf16x4 a1h = *(const bf16x4*)(vbase1 + c*32 + 16 + quad*4);
            bf16x8 B8 = mk8(pbw[2*c][0], pbw[2*c][1], pbw[2*c+1][0], pbw[2*c+1][1]);
            o0 = MF(cat44(a0l, a0h), B8, o0);
            o1 = MF(cat44(a1l, a1h), B8, o1);
          }
          {
            // tail: tile 12; B upper half is zero, so A upper half may be
            // any finite data -> re-read cols 192..207 (no zero-fill needed)
            bf16x4 a0l = *(const bf16x4*)(vbase0 + 192 + quad*4);
            bf16x4 a1l = *(const bf16x4*)(vbase1 + 192 + quad*4);
            bf16x8 B8 = mk8(pbw[12][0], pbw[12][1], 0u, 0u);
            o0 = MF(cat44(a0l, a0l), B8, o0);
            o1 = MF(cat44(a1l, a1l), B8, o1);
          }

          // X[row=m16+l16][cols quad*4..+3 and 16+quad*4..+3] += inv*O^T + ob
          u32* xr = (u32*)(Xb + (m16+l16)*XST);
          {
            u32 d0 = xr[quad*2], d1 = xr[quad*2+1];
            f32x2 r01 = f32x2{o0[0],o0[1]} * inv + (upk2(d0) + f32x2{ob0[0],ob0[1]});
            f32x2 r23 = f32x2{o0[2],o0[3]} * inv + (upk2(d1) + f32x2{ob0[2],ob0[3]});
            xr[quad*2]   = pk2bf(r01);
            xr[quad*2+1] = pk2bf(r23);
            u32 d2 = xr[8+quad*2], d3 = xr[8+quad*2+1];
            f32x2 s01 = f32x2{o1[0],o1[1]} * inv + (upk2(d2) + f32x2{ob1[0],ob1[1]});
            f32x2 s23 = f32x2{o1[2],o1[3]} * inv + (upk2(d3) + f32x2{ob1[2],ob1[3]});
            xr[8+quad*2]   = pk2bf(s01);
            xr[8+quad*2+1] = pk2bf(s23);
          }
        }
      }
    }
    __syncthreads();

    // ===== Phase D: LN2 stats =====
    ln_stats(Xb, MS, RS, tid);
    __syncthreads();

    // ===== Phase E: MLP, register-resident H, packed silu, bias in C =====
    {
      f32x2 G2[4], B2[4];
      #pragma unroll
      for (int p=0;p<4;p++){
        G2[p] = f32x2{BIAS[160+quad*8+2*p], BIAS[160+quad*8+2*p+1]};
        B2[p] = f32x2{BIAS[192+quad*8+2*p], BIAS[192+quad*8+2*p+1]};
      }
      bf16x8 anc[4];
      #pragma unroll
      for (int t=0;t<4;t++){
        int m = w + 4*t;
        if (m < NMT) anc[t] = build_nfrag(Xb, MS, RS, m*16+l16, quad, G2, B2);
      }
      f32x4 oacc[4][2];
      #pragma unroll
      for (int t=0;t<4;t++){ oacc[t][0] = Z; oacc[t][1] = Z; }
      const char* w1f = wsl + 8*1024;
      const char* w2f = wsl + 40*1024;
      const float* BW1 = (const float*)((const char*)ws + WS_B1) + l*HIDN;

      for (int hp = 0; hp < 16; ++hp){
        bf16x8 a1lo = *(const bf16x8*)(w1f + (2*hp  )*1024 + lane*16);
        bf16x8 a1hi = *(const bf16x8*)(w1f + (2*hp+1)*1024 + lane*16);
        bf16x8 a2e0 = *(const bf16x8*)(w2f + (hp*2  )*1024 + lane*16);
        bf16x8 a2e1 = *(const bf16x8*)(w2f + (hp*2+1)*1024 + lane*16);
        f32x4 b1q0 = *(const f32x4*)(BW1 + hp*32      + quad*4);
        f32x4 b1q1 = *(const f32x4*)(BW1 + hp*32 + 16 + quad*4);
        #pragma unroll
        for (int t=0;t<4;t++){
          int m = w + 4*t;
          if (m < NMT){
            f32x4 z0 = MF(a1lo, anc[t], b1q0);   // bias in C (exact)
            f32x4 z1 = MF(a1hi, anc[t], b1q1);
            bf16x8 H8 = mk8(spk(f32x2{z0[0], z0[1]}), spk(f32x2{z0[2], z0[3]}),
                            spk(f32x2{z1[0], z1[1]}), spk(f32x2{z1[2], z1[3]}));
            oacc[t][0] = MF(a2e0, H8, oacc[t][0]);
            oacc[t][1] = MF(a2e1, H8, oacc[t][1]);
          }
        }
      }

      // O^T C-layout: rows = e (quad*4+r), cols = seq (l16) — Phase-C-style RMW
      f32x4 b2q0 = *(const f32x4*)(BIAS + 224 + quad*4);
      f32x4 b2q1 = *(const f32x4*)(BIAS + 240 + quad*4);
      #pragma unroll
      for (int t=0;t<4;t++){
        int m = w + 4*t;
        if (m < NMT){
          u32* xr = (u32*)(Xb + (m*16 + l16)*XST);
          u32 d0 = xr[quad*2], d1 = xr[quad*2+1];
          f32x2 r01 = f32x2{oacc[t][0][0], oacc[t][0][1]} + (upk2(d0) + f32x2{b2q0[0], b2q0[1]});
          f32x2 r23 = f32x2{oacc[t][0][2], oacc[t][0][3]} + (upk2(d1) + f32x2{b2q0[2], b2q0[3]});
          xr[quad*2]   = pk2bf(r01);
          xr[quad*2+1] = pk2bf(r23);
          u32 d2 = xr[8+quad*2], d3 = xr[8+quad*2+1];
          f32x2 s01 = f32x2{oacc[t][1][0], oacc[t][1][1]} + (upk2(d2) + f32x2{b2q1[0], b2q1[1]});
          f32x2 s23 = f32x2{oacc[t][1][2], oacc[t][1][3]} + (upk2(d3) + f32x2{b2q1[2], b2q1[3]});
          xr[8+quad*2]   = pk2bf(s01);
          xr[8+quad*2+1] = pk2bf(s23);
        }
      }
    }
    __syncthreads();
  }

  // ===== final head =====
  const float* FW = (const float*)((const char*)ws + WS_FIN);
  if (tid < 32){
    BIAS[tid]    = FW[tid];
    BIAS[32+tid] = FW[32+tid];
    BIAS[64+tid] = FW[64+tid];
  }
  __syncthreads();
  float part = 0.f;
  if (tid < SS){
    const u32* row = (const u32*)(Xb + tid*XST);
    f32x2 v[16]; f32x2 s2 = {0.f,0.f};
    #pragma unroll
    for (int i=0;i<16;i++){ f32x2 p = upk2(row[i]); v[i] = p; s2 += p; }
    float m = (s2.x+s2.y) * (1.f/EE);
    f32x2 m2 = {m,m};
    f32x2 var2 = {0.f,0.f};
    #pragma unroll
    for (int i=0;i<16;i++){ f32x2 d = v[i]-m2; var2 += d*d; }
    float rs = rsqrtf((var2.x+var2.y)*(1.f/EE) + 1e-5f);
    f32x2 rs2 = {rs, rs};
    f32x2 dot2 = {0.f,0.f};
    #pragma unroll
    for (int i=0;i<16;i++){
      f32x2 g  = {BIAS[2*i], BIAS[2*i+1]};
      f32x2 bb = {BIAS[32+2*i], BIAS[33+2*i]};
      f32x2 wp = {BIAS[64+2*i], BIAS[65+2*i]};
      dot2 += ((v[i]-m2)*rs2*g + bb) * wp;
    }
    part = dot2.x + dot2.y + FW[96];
  }
  #pragma unroll
  for (int off=32; off; off>>=1) part += __shfl_xor(part, off);
  float* REDF = (float*)(smem + MS_OFF);
  __syncthreads();
  if (lane == 0) REDF[w] = part;
  __syncthreads();
  if (tid == 0){
    float u = REDF[0] + REDF[1] + REDF[2] + REDF[3];
    int ex = expid[b];
    float corr = FW[257+ex];
    #pragma unroll
    for (int c = 0; c < CWN; ++c){
      float pre = u * FW[97+c] + FW[113+c];
      pre = pre > 0.f ? pre : (__expf(pre) - 1.f);
      corr += pre * FW[129 + ex*CWN + c];
    }
    float res = corr + u;
    if (F32) ((float*)out)[b] = res;
    else     ((u16*)out)[b]  = f2bf(res);
  }
}

__global__ __launch_bounds__(256, 3) void tr_kernel(
    const int* __restrict__ seq, const int* __restrict__ expid,
    const void* __restrict__ tok_emb, const void* __restrict__ pos_emb,
    const void* __restrict__ ws, void* __restrict__ out)
{
  __shared__ __align__(16) unsigned char smem[SMEM_SZ];
  if (sniff_bf16(tok_emb, threadIdx.x))
    tr_body<false>(seq, expid, tok_emb, pos_emb, ws, out, smem);
  else
    tr_body<true >(seq, expid, tok_emb, pos_emb, ws, out, smem);
}

extern "C" void kernel_launch(void* const* d_in, const int* in_sizes, int n_in,
                              void* d_out, int out_size, void* d_ws, size_t ws_size,
                              hipStream_t stream)
{
  (void)in_sizes; (void)n_in; (void)ws_size; (void)out_size;
  const void* tok_emb = d_in[2];
  fmt_frags<<<dim3(288), dim3(64), 0, stream>>>(
      tok_emb, d_in[6], d_in[7], d_in[8], d_in[12], d_in[16], d_in[18], d_ws);
  fmt_bias<<<dim3(1), dim3(256), 0, stream>>>(
      tok_emb, d_in[9], d_in[10], d_in[11], d_in[12], d_in[13],
      d_in[4], d_in[5], d_in[14], d_in[15], d_in[17], d_in[19],
      d_in[20], d_in[21], d_in[22], d_in[23],
      d_in[24], d_in[25], d_in[26], d_in[27], d_ws);
  tr_kernel<<<dim3(BB), dim3(256), 0, stream>>>(
      (const int*)d_in[0], (const int*)d_in[1], tok_emb, d_in[3], d_ws, d_out);
}